// Round 10
// baseline (1744.821 us; speedup 1.0000x reference)
//
#include <hip/hip_runtime.h>
#include <math.h>

#define HH 4096
#define WW 4096
#define NB 64
#define U 8
#define NGR (WW / U)    // 512 groups
#define GATE 48         // consumer starts once producer published column GATE
#define ORING 256       // LDS out-ring columns (wave0 -> courier)
#define IRING 128       // LDS in-ring columns (courier -> wave0)

// Global halo: halo[(blk*WW + col)*2 + s]; s=0 -> row 62 (consumer r-2),
// s=1 -> row 63 (r-1). Value after column col-1 (col=0 = initial x).
// Entry: low32 = float bits, high32 = tag (col+1). Poison never matches tags.
//
// Scan wave (wave 0) does ONLY loads on VMEM; all global atomics (publish +
// prefetch) run on the courier wave (wave 1), decoupled through LDS rings.
// Rationale: rounds 5-9 showed per-column cost pinned at ~143ns independent of
// chain length/clock => scan wave's vmcnt FIFO saturated by slow-acking
// publish atomics; issue rate locked to atomic RT. Courier absorbs that RT.

__device__ __forceinline__ float f4c(const float4& v, int k) {
    return (k == 0) ? v.x : ((k == 1) ? v.y : ((k == 2) ? v.z : v.w));
}

// shift all 64 lanes down by 1 at VALU speed; lane 0 receives fill's lane-0 value.
__device__ __forceinline__ float wave_shr1(float src, float fill) {
    return __int_as_float(__builtin_amdgcn_update_dpp(
        __float_as_int(fill), __float_as_int(src), 0x138, 0xF, 0xF, false));
}

// HW sin: v_sin_f32 computes sin(2*pi*x). |z| <= 3 -> no range reduction.
__device__ __forceinline__ float fast_sin(float z) {
    return __builtin_amdgcn_sinf(z * 0.15915494309189535f);  // 1/(2*pi)
}

#define COLSTEP(COL, M, WB, K)                                               \
    do {                                                                     \
        float am1 = wave_shr1(a, Hhi[M][K]);                                 \
        float am2 = wave_shr1(am1, Hlo[M][K]);                               \
        const float z = fmaf(am2, f4c(W2v[WB][(K) >> 2], (K) & 3),           \
                        fmaf(am1, f4c(W1v[WB][(K) >> 2], (K) & 3),           \
                        fmaf(a,   f4c(Wv[WB][(K) >> 2],  (K) & 3),           \
                                  f4c(Bv[WB][(K) >> 2],  (K) & 3))));        \
        a = fast_sin(z);                                                     \
        if (lane >= 62 && (COL) + 1 < WW) {                                  \
            const int _oi = ((((COL) + 1) & (ORING - 1)) << 1) + (lane - 62);\
            vOutVal[_oi] = __float_as_uint(a);   /* value first */           \
            vOutTag[_oi] = (unsigned)((COL) + 2);/* then tag (volatile ord) */\
        }                                                                    \
    } while (0)

#define LOADW(WB, J)                                                         \
    do {                                                                     \
        const int _j = (J);                                                  \
        Wv[WB][0]  = *(const float4*)(wp  + _j);                             \
        Wv[WB][1]  = *(const float4*)(wp  + _j + 4);                         \
        W1v[WB][0] = *(const float4*)(wp1 + _j);                             \
        W1v[WB][1] = *(const float4*)(wp1 + _j + 4);                         \
        W2v[WB][0] = *(const float4*)(wp2 + _j);                             \
        W2v[WB][1] = *(const float4*)(wp2 + _j + 4);                         \
        Bv[WB][0]  = *(const float4*)(bp  + _j);                             \
        Bv[WB][1]  = *(const float4*)(bp  + _j + 4);                         \
    } while (0)

// tag-check + broadcast-unpack group GIDX's halo from the LDS in-ring into
// Hlo[BUF]/Hhi[BUF]. Pure LDS. One group ahead of use; courier fills ~32-64
// columns ahead, so the spin is a rare transient.
#define UNPACKG(GIDX, BUF)                                                   \
    do {                                                                     \
        if (blk > 0) {                                                       \
            const int _col = (GIDX) * U + (lane >> 1);                       \
            const int _ii  = ((_col & (IRING - 1)) << 1) + (lane & 1);       \
            unsigned _tag = 0;                                               \
            for (;;) {                                                       \
                if (lane < 16) _tag = vInTag[_ii];                           \
                bool _ok = (lane >= 16) || (_tag == (unsigned)(_col + 1));   \
                if (__all(_ok)) break;                                       \
                __builtin_amdgcn_s_sleep(1);                                 \
            }                                                                \
            unsigned _val = 0;                                               \
            if (lane < 16) _val = vInVal[_ii];                               \
            float _hv = __uint_as_float(_val);                               \
            _Pragma("unroll")                                                \
            for (int k = 0; k < U; ++k) {                                    \
                Hlo[BUF][k] = __shfl(_hv, 2 * k);                            \
                Hhi[BUF][k] = __shfl(_hv, 2 * k + 1);                        \
            }                                                                \
        }                                                                    \
    } while (0)

#define GROUPBODY(S)                                                         \
    do {                                                                     \
        const int G  = g4 * 4 + (S);                                         \
        const int jb = G * U;                                                \
        if (G + 1 < NGR) UNPACKG(G + 1, ((S) + 1) & 1);                      \
        _Pragma("unroll")                                                    \
        for (int k = 0; k < U; ++k) COLSTEP(jb + k, (S) & 1, S, k);          \
        const int jw = jb + 4 * U;                                           \
        if (jw < WW) LOADW(S, jw);                                           \
        /* out-ring overrun guard: next group writes out-cols <= jb+16;    */\
        /* slot reuse needs courier done > jb+16-ORING (margin 8).         */\
        unsigned _done = vOutDone[0];                                        \
        while (__builtin_expect((int)(jb + 2 * U) > (int)_done + (ORING - 8),\
                                0)) {                                        \
            __builtin_amdgcn_s_sleep(4);                                     \
            _done = vOutDone[0];                                             \
        }                                                                    \
    } while (0)

__global__ __launch_bounds__(128, 1) void neural_grid_scan(
    const float* __restrict__ x, const float* __restrict__ w,
    const float* __restrict__ bb, float* __restrict__ out,
    unsigned long long* __restrict__ halo)
{
    __shared__ unsigned ldsOutVal[ORING * 2];
    __shared__ unsigned ldsOutTag[ORING * 2];
    __shared__ unsigned ldsInVal[IRING * 2];
    __shared__ unsigned ldsInTag[IRING * 2];
    __shared__ unsigned ldsOutDone[1];

    volatile unsigned* vOutVal = ldsOutVal;
    volatile unsigned* vOutTag = ldsOutTag;
    volatile unsigned* vInVal  = ldsInVal;
    volatile unsigned* vInTag  = ldsInTag;
    volatile unsigned* vOutDone = ldsOutDone;

    const int wv   = threadIdx.x >> 6;
    const int lane = threadIdx.x & 63;
    const int blk  = blockIdx.x;

    // zero LDS tags (LDS contents are undefined at launch)
    for (int i = threadIdx.x; i < ORING * 2; i += 128) ldsOutTag[i] = 0;
    for (int i = threadIdx.x; i < IRING * 2; i += 128) ldsInTag[i] = 0;
    if (threadIdx.x == 0) ldsOutDone[0] = 0;
    __syncthreads();

    unsigned long long* hme  = halo + (size_t)blk * WW * 2;
    unsigned long long* hsrc = halo + (size_t)(blk - 1) * WW * 2;

    if (wv == 1) {
        // ================= courier wave =================
        int cO = 0;                         // next out column to publish
        int cI = (blk > 0) ? 0 : WW;        // next in column to fetch
        const int colOfs = lane >> 1;
        const int slot   = lane & 1;
        while (cO < WW || cI < WW) {
            bool prog = false;
            if (cO < WW) {
                const int col = cO + colOfs;
                const int oi  = ((col & (ORING - 1)) << 1) + slot;
                unsigned tag = vOutTag[oi];
                if (__all(tag == (unsigned)(col + 1))) {
                    unsigned val = vOutVal[oi];
                    atomicExch(&hme[(size_t)col * 2 + slot],
                               ((unsigned long long)tag << 32) |
                               (unsigned long long)val);
                    cO += 32;
                    if (lane == 0) vOutDone[0] = (unsigned)cO;
                    prog = true;
                }
            }
            if (cI < WW && cI < cO + 96) {
                const int col = cI + colOfs;
                unsigned long long got =
                    atomicOr(&hsrc[(size_t)col * 2 + slot], 0ULL);
                if (__all((unsigned)(got >> 32) == (unsigned)(col + 1))) {
                    const int ii = ((col & (IRING - 1)) << 1) + slot;
                    vInVal[ii] = (unsigned)(got & 0xffffffffu);  // value first
                    vInTag[ii] = (unsigned)(got >> 32);          // then tag
                    cI += 32;
                    prog = true;
                }
            }
            if (!prog) __builtin_amdgcn_s_sleep(2);
        }
        return;
    }

    // ================= scan wave (wave 0) =================
    const int row = blk * 64 + lane;
    const int r1 = (row >= 1) ? row - 1 : 0;   // am1==0 there, value unused
    const int r2 = (row >= 2) ? row - 2 : 0;

    const float* wp  = w  + (size_t)row * WW;
    const float* wp1 = w  + (size_t)r1  * WW;
    const float* wp2 = w  + (size_t)r2  * WW;
    const float* bp  = bb + (size_t)row * WW;

    float a = x[row];

    // seed out-ring col 0 (initial x, tag 1)
    if (lane >= 62) {
        vOutVal[lane - 62] = __float_as_uint(a);
        vOutTag[lane - 62] = 1u;
    }

    // start gate: producer must be GATE columns ahead (keeps courier's in-ring
    // fill permanently fresh -> no retry storms on the steady-state path)
    if (blk > 0 && lane == 0) {
        while ((unsigned)(atomicOr(&hsrc[(size_t)GATE * 2], 0ULL) >> 32)
               != (unsigned)(GATE + 1)) {
            __builtin_amdgcn_s_sleep(8);
        }
    }

    float4 Wv[4][2], W1v[4][2], W2v[4][2], Bv[4][2];   // 4-group W/B ring
    float Hlo[2][U] = {}, Hhi[2][U] = {};

    LOADW(0, 0);
    LOADW(1, U);
    LOADW(2, 2 * U);
    LOADW(3, 3 * U);
    UNPACKG(0, 0);   // group 0 -> halo buf 0

    for (int g4 = 0; g4 < NGR / 4; ++g4) {
        GROUPBODY(0);
        GROUPBODY(1);
        GROUPBODY(2);
        GROUPBODY(3);
    }

    out[row] = a;
}

extern "C" void kernel_launch(void* const* d_in, const int* in_sizes, int n_in,
                              void* d_out, int out_size, void* d_ws, size_t ws_size,
                              hipStream_t stream) {
    const float* x = (const float*)d_in[0];
    const float* w = (const float*)d_in[1];
    const float* b = (const float*)d_in[2];
    float* out = (float*)d_out;
    unsigned long long* halo = (unsigned long long*)d_ws;
    neural_grid_scan<<<dim3(NB), dim3(128), 0, stream>>>(x, w, b, out, halo);
}